// Round 4
// baseline (335.197 us; speedup 1.0000x reference)
//
#include <hip/hip_runtime.h>

#define N_NODES 50000
#define N_EDGES 600000

typedef short bf16x8 __attribute__((ext_vector_type(8)));
typedef float f32x4  __attribute__((ext_vector_type(4)));
typedef unsigned short u16x8 __attribute__((ext_vector_type(8)));
typedef unsigned short u16x4 __attribute__((ext_vector_type(4)));

// ---------------- bf16 helpers (RNE) ----------------
__device__ inline ushort rne_bf16(float a) {
    union { float f; unsigned u; } v; v.f = a;
    return (ushort)((v.u + 0x7FFFu + ((v.u >> 16) & 1u)) >> 16);
}
__device__ inline float bf16_to_f32(ushort h) {
    return __uint_as_float((unsigned)h << 16);
}
__device__ inline void split_bf16(float a, ushort& hi, ushort& lo) {
    hi = rne_bf16(a);
    float hv = bf16_to_f32(hi);
    lo = rne_bf16(a - hv);
}

// ---------------- CSR build ----------------

__global__ void count_deg_kernel(const int* __restrict__ dst, int* __restrict__ deg, int ne) {
    int e = blockIdx.x * blockDim.x + threadIdx.x;
    if (e < ne) atomicAdd(&deg[dst[e]], 1);
}

__global__ __launch_bounds__(256) void block_sums_kernel(const int* __restrict__ deg,
                                                         int* __restrict__ bsum, int n) {
    __shared__ int s[256];
    int t = threadIdx.x;
    int i = blockIdx.x * 256 + t;
    s[t] = (i < n) ? deg[i] : 0;
    __syncthreads();
    #pragma unroll
    for (int d = 128; d > 0; d >>= 1) {
        if (t < d) s[t] += s[t + d];
        __syncthreads();
    }
    if (t == 0) bsum[blockIdx.x] = s[0];
}

// Fused: re-scan the 196 block sums per block (cheap), then per-block scan of deg.
__global__ __launch_bounds__(256) void scatter_fused_kernel(const int* __restrict__ deg,
                                                            const int* __restrict__ bsum,
                                                            int* __restrict__ off,
                                                            int* __restrict__ cur,
                                                            int n, int nb) {
    __shared__ int s[256];
    int t = threadIdx.x;

    // scan of block sums
    int bv = (t < nb) ? bsum[t] : 0;
    s[t] = bv;
    __syncthreads();
    #pragma unroll
    for (int d = 1; d < 256; d <<= 1) {
        int x = (t >= d) ? s[t - d] : 0;
        __syncthreads();
        s[t] += x;
        __syncthreads();
    }
    int base = (blockIdx.x > 0) ? s[blockIdx.x - 1] : 0;   // exclusive base for this block
    if (blockIdx.x == 0 && t == 0) off[n] = s[255];        // total edges
    __syncthreads();

    // per-block scan of deg
    int i = blockIdx.x * 256 + t;
    int v = (i < n) ? deg[i] : 0;
    s[t] = v;
    __syncthreads();
    #pragma unroll
    for (int d = 1; d < 256; d <<= 1) {
        int x = (t >= d) ? s[t - d] : 0;
        __syncthreads();
        s[t] += x;
        __syncthreads();
    }
    if (i < n) {
        int excl = s[t] - v + base;
        off[i] = excl;
        cur[i] = excl;
    }
}

__global__ void fill_csr_kernel(const int* __restrict__ src, const int* __restrict__ dst,
                                int* __restrict__ cur, int* __restrict__ ssrc, int ne) {
    int e = blockIdx.x * blockDim.x + threadIdx.x;
    if (e < ne) {
        int p = atomicAdd(&cur[dst[e]], 1);
        ssrc[p] = src[e];
    }
}

// ---------------- weight pre-convert (all 3 layers, one dispatch) ----------------
__global__ void convert_all_w(const float* __restrict__ ws0, const float* __restrict__ wn0,
                              const float* __restrict__ ws1, const float* __restrict__ wn1,
                              const float* __restrict__ ws2, const float* __restrict__ wn2,
                              ushort* __restrict__ Bth0, ushort* __restrict__ Btl0,
                              ushort* __restrict__ Bth1, ushort* __restrict__ Btl1,
                              ushort* __restrict__ Bth2, ushort* __restrict__ Btl2) {
    int b = blockIdx.x;
    int k = threadIdx.x;
    const float *Ws, *Wn;
    ushort *H, *L;
    int dout, n;
    if (b < 256)      { n = b;       dout = 128; Ws = ws0; Wn = wn0; H = Bth0; L = Btl0; }
    else if (b < 512) { n = b - 256; dout = 128; Ws = ws1; Wn = wn1; H = Bth1; L = Btl1; }
    else              { n = b - 512; dout = 40;  Ws = ws2; Wn = wn2; H = Bth2; L = Btl2; }
    float w = (n < dout) ? Ws[(long)k * dout + n] : Wn[(long)k * dout + (n - dout)];
    ushort hi, lo;
    split_bf16(w, hi, lo);
    H[n * 128 + k] = hi;
    L[n * 128 + k] = lo;
}

// ---------------- split-bf16 MFMA dual GEMM ----------------
// 32-row tiles (1563 blocks -> ~6 blocks/CU of TLP; the 64-row version was
// grid-limited to 3 blocks/CU and exposed the full B-load latency 16x/block).
// Full-K (128) A-tile staged once in LDS as hi/lo bf16; MFMA operands SWAPPED
// (weight as A-operand) -> lane owns 4 consecutive output cols -> 16B/8B stores.
// Triple-product split keeps numerics identical across restructures.

#define KDIM 128
#define APAD 136   // 128 + 8 ushorts pad

// stage 32 rows x 128 cols: thread t loads row t>>3, 16 floats at (t&7)*16.
__device__ inline void stage_a32(const float* __restrict__ A, int bm, int M, int tid,
                                 ushort* __restrict__ Ahi, ushort* __restrict__ Alo) {
    const int m   = tid >> 3;            // 0..31
    const int seg = (tid & 7) * 16;      // float offset
    const int grow = bm + m;
    float f[16];
    if (grow < M) {
        const float* ap = A + (long)grow * KDIM + seg;
        #pragma unroll
        for (int q = 0; q < 4; ++q) {
            float4 a = *(const float4*)(ap + q * 4);
            f[q * 4 + 0] = a.x; f[q * 4 + 1] = a.y;
            f[q * 4 + 2] = a.z; f[q * 4 + 3] = a.w;
        }
    } else {
        #pragma unroll
        for (int i = 0; i < 16; ++i) f[i] = 0.f;
    }
    ushort h[16], l[16];
    #pragma unroll
    for (int i = 0; i < 16; ++i) split_bf16(f[i], h[i], l[i]);
    #pragma unroll
    for (int q = 0; q < 2; ++q) {
        uint4 hw, lw;
        hw.x = (unsigned)h[q*8+0] | ((unsigned)h[q*8+1] << 16);
        hw.y = (unsigned)h[q*8+2] | ((unsigned)h[q*8+3] << 16);
        hw.z = (unsigned)h[q*8+4] | ((unsigned)h[q*8+5] << 16);
        hw.w = (unsigned)h[q*8+6] | ((unsigned)h[q*8+7] << 16);
        lw.x = (unsigned)l[q*8+0] | ((unsigned)l[q*8+1] << 16);
        lw.y = (unsigned)l[q*8+2] | ((unsigned)l[q*8+3] << 16);
        lw.z = (unsigned)l[q*8+4] | ((unsigned)l[q*8+5] << 16);
        lw.w = (unsigned)l[q*8+6] | ((unsigned)l[q*8+7] << 16);
        *(uint4*)&Ahi[m * APAD + seg + q * 8] = hw;
        *(uint4*)&Alo[m * APAD + seg + q * 8] = lw;
    }
}

// Wide: dout=128 dual (256 cols). Block = 32 rows x 256 cols, wave = 32 rows x 64 cols.
__global__ __launch_bounds__(256, 4) void gemm_mfma_wide(
    const float* __restrict__ A,
    const ushort* __restrict__ Bth, const ushort* __restrict__ Btl,
    const float* __restrict__ bias,
    float* __restrict__ S, ushort* __restrict__ T, int M)
{
    __shared__ ushort Ahi[32 * APAD];
    __shared__ ushort Alo[32 * APAD];

    const int tid = threadIdx.x;
    const int wave = tid >> 6;
    const int lane = tid & 63;
    const int lane16 = lane & 15;
    const int quad = lane >> 4;
    const int bm = blockIdx.x * 32;
    const int colbase = wave * 64;

    stage_a32(A, bm, M, tid, Ahi, Alo);
    __syncthreads();

    f32x4 acc[2][4] = {};

    #pragma unroll
    for (int c = 0; c < 4; ++c) {
        const int k0 = c * 32 + quad * 8;
        bf16x8 ah[2], al[2];
        #pragma unroll
        for (int r = 0; r < 2; ++r) {
            int off = (16 * r + lane16) * APAD + k0;
            ah[r] = *(const bf16x8*)&Ahi[off];
            al[r] = *(const bf16x8*)&Alo[off];
        }
        #pragma unroll
        for (int ct = 0; ct < 4; ++ct) {
            const long boff = (long)(colbase + 16 * ct + lane16) * KDIM + k0;
            bf16x8 bh = *(const bf16x8*)(Bth + boff);
            bf16x8 bl = *(const bf16x8*)(Btl + boff);
            #pragma unroll
            for (int r = 0; r < 2; ++r) {
                acc[r][ct] = __builtin_amdgcn_mfma_f32_16x16x32_bf16(bh, ah[r], acc[r][ct], 0, 0, 0);
                acc[r][ct] = __builtin_amdgcn_mfma_f32_16x16x32_bf16(bl, ah[r], acc[r][ct], 0, 0, 0);
                acc[r][ct] = __builtin_amdgcn_mfma_f32_16x16x32_bf16(bh, al[r], acc[r][ct], 0, 0, 0);
            }
        }
    }

    // Swapped C/D mapping: acc[r][ct][i] = C[bm+16r+lane16][colbase+16ct+quad*4+i]
    #pragma unroll
    for (int ct = 0; ct < 4; ++ct) {
        const int col0 = colbase + 16 * ct + quad * 4;
        const bool toS = col0 < 128;
        f32x4 bv = {0,0,0,0};
        if (toS) bv = *(const f32x4*)(bias + col0);
        #pragma unroll
        for (int r = 0; r < 2; ++r) {
            const int row = bm + 16 * r + lane16;
            if (row < M) {
                if (toS) {
                    *(f32x4*)(S + (long)row * 128 + col0) = acc[r][ct] + bv;
                } else {
                    u16x4 t4;
                    #pragma unroll
                    for (int i = 0; i < 4; ++i) t4[i] = rne_bf16(acc[r][ct][i]);
                    *(u16x4*)(T + (long)row * 128 + (col0 - 128)) = t4;
                }
            }
        }
    }
}

// Narrow: dout=40 dual (80 cols). Block = 32 rows; wave (rt,cg): rows rt*16,
// cols cg ? {ct3,ct4} : {ct0,ct1,ct2}.
__global__ __launch_bounds__(256, 4) void gemm_mfma_narrow(
    const float* __restrict__ A,
    const ushort* __restrict__ Bth, const ushort* __restrict__ Btl,
    const float* __restrict__ bias,
    float* __restrict__ S, ushort* __restrict__ T, int M)
{
    __shared__ ushort Ahi[32 * APAD];
    __shared__ ushort Alo[32 * APAD];

    const int tid = threadIdx.x;
    const int wave = tid >> 6;
    const int lane = tid & 63;
    const int lane16 = lane & 15;
    const int quad = lane >> 4;
    const int bm = blockIdx.x * 32;

    const int rt = wave & 1;         // row-tile 0/1
    const int cg = wave >> 1;        // col-group 0/1
    const int ctbase = cg * 3;       // 0 or 3
    const int nct = cg ? 2 : 3;

    stage_a32(A, bm, M, tid, Ahi, Alo);
    __syncthreads();

    f32x4 acc[3] = {};

    #pragma unroll
    for (int c = 0; c < 4; ++c) {
        const int off = (rt * 16 + lane16) * APAD + c * 32 + quad * 8;
        bf16x8 ah = *(const bf16x8*)&Ahi[off];
        bf16x8 al = *(const bf16x8*)&Alo[off];
        #pragma unroll
        for (int j = 0; j < 3; ++j) {
            if (j < nct) {
                const int ct = ctbase + j;
                const long boff = (long)(16 * ct + lane16) * KDIM + c * 32 + quad * 8;
                bf16x8 bh = *(const bf16x8*)(Bth + boff);
                bf16x8 bl = *(const bf16x8*)(Btl + boff);
                acc[j] = __builtin_amdgcn_mfma_f32_16x16x32_bf16(bh, ah, acc[j], 0, 0, 0);
                acc[j] = __builtin_amdgcn_mfma_f32_16x16x32_bf16(bl, ah, acc[j], 0, 0, 0);
                acc[j] = __builtin_amdgcn_mfma_f32_16x16x32_bf16(bh, al, acc[j], 0, 0, 0);
            }
        }
    }

    #pragma unroll
    for (int j = 0; j < 3; ++j) {
        if (j < nct) {
            const int ct = ctbase + j;
            const int col0 = 16 * ct + quad * 4;
            const bool toS = col0 < 40;
            const int row = bm + rt * 16 + lane16;
            if (row < M) {
                if (toS) {
                    f32x4 bv = *(const f32x4*)(bias + col0);
                    *(f32x4*)(S + (long)row * 40 + col0) = acc[j] + bv;
                } else {
                    u16x4 t4;
                    #pragma unroll
                    for (int i = 0; i < 4; ++i) t4[i] = rne_bf16(acc[j][i]);
                    *(u16x4*)(T + (long)row * 40 + (col0 - 40)) = t4;
                }
            }
        }
    }
}

// ---------------- aggregation, wave-per-node, bf16 gather ----------------

template <int RELU>
__global__ __launch_bounds__(256) void agg128_kernel(
    const float* __restrict__ S, const ushort* __restrict__ T,
    const int* __restrict__ off, const int* __restrict__ ssrc,
    float* __restrict__ out, int nnodes)
{
    const int node = (blockIdx.x * 256 + threadIdx.x) >> 6;
    if (node >= nnodes) return;
    const int lane = threadIdx.x & 63;
    const int slot = lane >> 4;          // 0..3
    const int col8 = (lane & 15) * 8;    // 8 features per lane

    const int a = off[node];
    const int b = off[node + 1];

    f32x4 acc0a = {0,0,0,0}, acc0b = {0,0,0,0};
    f32x4 acc1a = {0,0,0,0}, acc1b = {0,0,0,0};

    int i = a;
    for (; i + 8 <= b; i += 8) {
        int s0 = ssrc[i + slot];
        int s1 = ssrc[i + 4 + slot];
        u16x8 v0 = *(const u16x8*)(T + (long)s0 * 128 + col8);
        u16x8 v1 = *(const u16x8*)(T + (long)s1 * 128 + col8);
        #pragma unroll
        for (int j = 0; j < 4; ++j) {
            acc0a[j] += bf16_to_f32(v0[j]);
            acc0b[j] += bf16_to_f32(v0[4 + j]);
            acc1a[j] += bf16_to_f32(v1[j]);
            acc1b[j] += bf16_to_f32(v1[4 + j]);
        }
    }
    for (; i < b; i += 4) {
        int e = i + slot;
        if (e < b) {
            int s = ssrc[e];
            u16x8 v = *(const u16x8*)(T + (long)s * 128 + col8);
            #pragma unroll
            for (int j = 0; j < 4; ++j) {
                acc0a[j] += bf16_to_f32(v[j]);
                acc0b[j] += bf16_to_f32(v[4 + j]);
            }
        }
    }
    f32x4 accA = acc0a + acc1a;
    f32x4 accB = acc0b + acc1b;

    // reduce across the 4 slots
    #pragma unroll
    for (int m = 16; m <= 32; m <<= 1) {
        #pragma unroll
        for (int j = 0; j < 4; ++j) {
            accA[j] += __shfl_xor((float)accA[j], m);
            accB[j] += __shfl_xor((float)accB[j], m);
        }
    }

    if (slot == 0) {
        int deg = b - a;
        float scale = (deg > 0) ? (1.0f / (float)deg) : 0.f;
        f32x4 sA = *(const f32x4*)(S + (long)node * 128 + col8);
        f32x4 sB = *(const f32x4*)(S + (long)node * 128 + col8 + 4);
        f32x4 rA = sA + accA * scale;
        f32x4 rB = sB + accB * scale;
        if (RELU) {
            #pragma unroll
            for (int j = 0; j < 4; ++j) {
                rA[j] = fmaxf(rA[j], 0.f);
                rB[j] = fmaxf(rB[j], 0.f);
            }
        }
        *(f32x4*)(out + (long)node * 128 + col8) = rA;
        *(f32x4*)(out + (long)node * 128 + col8 + 4) = rB;
    }
}

template <int RELU>
__global__ __launch_bounds__(256) void agg40_kernel(
    const float* __restrict__ S, const ushort* __restrict__ T,
    const int* __restrict__ off, const int* __restrict__ ssrc,
    float* __restrict__ out, int nnodes)
{
    const int node = (blockIdx.x * 256 + threadIdx.x) >> 6;
    if (node >= nnodes) return;
    const int lane = threadIdx.x & 63;
    const bool active = lane < 60;
    const int slot = active ? (lane / 10) : 5;   // 0..5
    const int fi = lane % 10;
    const int fo = fi * 4;

    const int a = off[node];
    const int b = off[node + 1];

    f32x4 acc0 = {0,0,0,0}, acc1 = {0,0,0,0};

    int i = a;
    for (; i + 12 <= b; i += 12) {
        int s0 = ssrc[i + slot];
        int s1 = ssrc[i + 6 + slot];
        u16x4 v0 = *(const u16x4*)(T + (long)s0 * 40 + fo);
        u16x4 v1 = *(const u16x4*)(T + (long)s1 * 40 + fo);
        if (active) {
            #pragma unroll
            for (int j = 0; j < 4; ++j) {
                acc0[j] += bf16_to_f32(v0[j]);
                acc1[j] += bf16_to_f32(v1[j]);
            }
        }
    }
    for (; i < b; i += 6) {
        int e = i + slot;
        if (active && e < b) {
            int s = ssrc[e];
            u16x4 v = *(const u16x4*)(T + (long)s * 40 + fo);
            #pragma unroll
            for (int j = 0; j < 4; ++j) acc0[j] += bf16_to_f32(v[j]);
        }
    }
    f32x4 acc = acc0 + acc1;

    f32x4 tot = acc;
    #pragma unroll
    for (int d = 10; d <= 50; d += 10) {
        int srcl = fi + d;
        #pragma unroll
        for (int j = 0; j < 4; ++j) tot[j] += __shfl((float)acc[j], srcl);
    }

    if (lane < 10) {
        int deg = b - a;
        float scale = (deg > 0) ? (1.0f / (float)deg) : 0.f;
        f32x4 s4 = *(const f32x4*)(S + (long)node * 40 + fo);
        f32x4 r = s4 + tot * scale;
        if (RELU) {
            #pragma unroll
            for (int j = 0; j < 4; ++j) r[j] = fmaxf(r[j], 0.f);
        }
        *(f32x4*)(out + (long)node * 40 + fo) = r;
    }
}

// ---------------- launch ----------------

extern "C" void kernel_launch(void* const* d_in, const int* in_sizes, int n_in,
                              void* d_out, int out_size, void* d_ws, size_t ws_size,
                              hipStream_t stream) {
    const float* feat = (const float*)d_in[0];
    const int*   src  = (const int*)d_in[1];
    const int*   dst  = (const int*)d_in[2];
    const float* ws0  = (const float*)d_in[3];
    const float* wn0  = (const float*)d_in[4];
    const float* b0   = (const float*)d_in[5];
    const float* ws1  = (const float*)d_in[6];
    const float* wn1  = (const float*)d_in[7];
    const float* b1   = (const float*)d_in[8];
    const float* ws2  = (const float*)d_in[9];
    const float* wn2  = (const float*)d_in[10];
    const float* b2   = (const float*)d_in[11];

    const int N = N_NODES;
    const int NE = N_EDGES;
    const int NB = (N + 255) / 256;  // 196

    char* ws = (char*)d_ws;
    int*    offsets = (int*)(ws + 0);
    int*    cursor  = (int*)(ws + 200704);
    int*    degi    = (int*)(ws + 401408);
    int*    bsum    = (int*)(ws + 601600);
    int*    ssrc    = (int*)(ws + 603648);
    ushort* Bth0 = (ushort*)(ws + 200704);   // overlap cursor/degi, written after CSR build
    ushort* Btl0 = (ushort*)(ws + 266240);
    ushort* Bth1 = (ushort*)(ws + 331776);
    ushort* Btl1 = (ushort*)(ws + 397312);
    ushort* Bth2 = (ushort*)(ws + 462848);
    ushort* Btl2 = (ushort*)(ws + 483328);
    float*  hbuf = (float*)(ws + 3003904);   // 25.6 MB fp32
    float*  sbuf = (float*)(ws + 28603904);  // 25.6 MB fp32
    ushort* tbuf = (ushort*)(ws + 54203904); // 12.8 MB bf16

    // ---- CSR build ----
    hipMemsetAsync(degi, 0, (size_t)N * sizeof(int), stream);
    count_deg_kernel<<<(NE + 255) / 256, 256, 0, stream>>>(dst, degi, NE);
    block_sums_kernel<<<NB, 256, 0, stream>>>(degi, bsum, N);
    scatter_fused_kernel<<<NB, 256, 0, stream>>>(degi, bsum, offsets, cursor, N, NB);
    fill_csr_kernel<<<(NE + 255) / 256, 256, 0, stream>>>(src, dst, cursor, ssrc, NE);

    // ---- weight pre-convert (one dispatch) ----
    convert_all_w<<<592, 128, 0, stream>>>(ws0, wn0, ws1, wn1, ws2, wn2,
                                           Bth0, Btl0, Bth1, Btl1, Bth2, Btl2);

    const int gx = (N + 31) / 32;        // 1563 GEMM blocks (32 rows each)
    const int ga = (N + 3) / 4;          // 12500 agg blocks (4 waves/block)

    // ---- layer 0 ----
    gemm_mfma_wide<<<gx, 256, 0, stream>>>(feat, Bth0, Btl0, b0, sbuf, tbuf, N);
    agg128_kernel<1><<<ga, 256, 0, stream>>>(sbuf, tbuf, offsets, ssrc, hbuf, N);

    // ---- layer 1 ----
    gemm_mfma_wide<<<gx, 256, 0, stream>>>(hbuf, Bth1, Btl1, b1, sbuf, tbuf, N);
    agg128_kernel<1><<<ga, 256, 0, stream>>>(sbuf, tbuf, offsets, ssrc, hbuf, N);

    // ---- layer 2 ----
    gemm_mfma_narrow<<<gx, 256, 0, stream>>>(hbuf, Bth2, Btl2, b2, sbuf, tbuf, N);
    agg40_kernel<0><<<ga, 256, 0, stream>>>(sbuf, tbuf, offsets, ssrc, (float*)d_out, N);
}

// Round 5
// 326.043 us; speedup vs baseline: 1.0281x; 1.0281x over previous
//
#include <hip/hip_runtime.h>

#define N_NODES 50000
#define N_EDGES 600000

typedef short bf16x8 __attribute__((ext_vector_type(8)));
typedef float f32x4  __attribute__((ext_vector_type(4)));
typedef unsigned short u16x8 __attribute__((ext_vector_type(8)));
typedef unsigned short u16x4 __attribute__((ext_vector_type(4)));

// ---------------- bf16 helpers (RNE) ----------------
__device__ inline ushort rne_bf16(float a) {
    union { float f; unsigned u; } v; v.f = a;
    return (ushort)((v.u + 0x7FFFu + ((v.u >> 16) & 1u)) >> 16);
}
__device__ inline float bf16_to_f32(ushort h) {
    return __uint_as_float((unsigned)h << 16);
}
__device__ inline void split_bf16(float a, ushort& hi, ushort& lo) {
    hi = rne_bf16(a);
    float hv = bf16_to_f32(hi);
    lo = rne_bf16(a - hv);
}

// ---------------- CSR build ----------------

__global__ void count_deg_kernel(const int* __restrict__ dst, int* __restrict__ deg, int ne) {
    int e = blockIdx.x * blockDim.x + threadIdx.x;
    if (e < ne) atomicAdd(&deg[dst[e]], 1);
}

__global__ __launch_bounds__(256) void block_sums_kernel(const int* __restrict__ deg,
                                                         int* __restrict__ bsum, int n) {
    __shared__ int s[256];
    int t = threadIdx.x;
    int i = blockIdx.x * 256 + t;
    s[t] = (i < n) ? deg[i] : 0;
    __syncthreads();
    #pragma unroll
    for (int d = 128; d > 0; d >>= 1) {
        if (t < d) s[t] += s[t + d];
        __syncthreads();
    }
    if (t == 0) bsum[blockIdx.x] = s[0];
}

// Fused: re-scan the 196 block sums per block (cheap), then per-block scan of deg.
__global__ __launch_bounds__(256) void scatter_fused_kernel(const int* __restrict__ deg,
                                                            const int* __restrict__ bsum,
                                                            int* __restrict__ off,
                                                            int* __restrict__ cur,
                                                            int n, int nb) {
    __shared__ int s[256];
    int t = threadIdx.x;

    // scan of block sums
    int bv = (t < nb) ? bsum[t] : 0;
    s[t] = bv;
    __syncthreads();
    #pragma unroll
    for (int d = 1; d < 256; d <<= 1) {
        int x = (t >= d) ? s[t - d] : 0;
        __syncthreads();
        s[t] += x;
        __syncthreads();
    }
    int base = (blockIdx.x > 0) ? s[blockIdx.x - 1] : 0;   // exclusive base for this block
    if (blockIdx.x == 0 && t == 0) off[n] = s[255];        // total edges
    __syncthreads();

    // per-block scan of deg
    int i = blockIdx.x * 256 + t;
    int v = (i < n) ? deg[i] : 0;
    s[t] = v;
    __syncthreads();
    #pragma unroll
    for (int d = 1; d < 256; d <<= 1) {
        int x = (t >= d) ? s[t - d] : 0;
        __syncthreads();
        s[t] += x;
        __syncthreads();
    }
    if (i < n) {
        int excl = s[t] - v + base;
        off[i] = excl;
        cur[i] = excl;
    }
}

__global__ void fill_csr_kernel(const int* __restrict__ src, const int* __restrict__ dst,
                                int* __restrict__ cur, int* __restrict__ ssrc, int ne) {
    int e = blockIdx.x * blockDim.x + threadIdx.x;
    if (e < ne) {
        int p = atomicAdd(&cur[dst[e]], 1);
        ssrc[p] = src[e];
    }
}

// ---------------- weight pre-convert (all 3 layers, one dispatch) ----------------
__global__ void convert_all_w(const float* __restrict__ ws0, const float* __restrict__ wn0,
                              const float* __restrict__ ws1, const float* __restrict__ wn1,
                              const float* __restrict__ ws2, const float* __restrict__ wn2,
                              ushort* __restrict__ Bth0, ushort* __restrict__ Btl0,
                              ushort* __restrict__ Bth1, ushort* __restrict__ Btl1,
                              ushort* __restrict__ Bth2, ushort* __restrict__ Btl2) {
    int b = blockIdx.x;
    int k = threadIdx.x;
    const float *Ws, *Wn;
    ushort *H, *L;
    int dout, n;
    if (b < 256)      { n = b;       dout = 128; Ws = ws0; Wn = wn0; H = Bth0; L = Btl0; }
    else if (b < 512) { n = b - 256; dout = 128; Ws = ws1; Wn = wn1; H = Bth1; L = Btl1; }
    else              { n = b - 512; dout = 40;  Ws = ws2; Wn = wn2; H = Bth2; L = Btl2; }
    float w = (n < dout) ? Ws[(long)k * dout + n] : Wn[(long)k * dout + (n - dout)];
    ushort hi, lo;
    split_bf16(w, hi, lo);
    H[n * 128 + k] = hi;
    L[n * 128 + k] = lo;
}

// ---------------- split-bf16 MFMA dual GEMM ----------------
// v5: B operand hoisted into REGISTERS, loaded once per block (the in-loop
// B global-loads were the invariant ~42us bottleneck across r0-r4: every
// k-iteration exposed a fresh ~250cy L2 round trip that no amount of TLP hid).
// Block = 256 threads, 4 waves x 32 cols = 128 cols; TWO blocks per 32-row
// tile: half 0 -> S cols 0-127, half 1 -> T cols 128-255 (S/T branch is
// block-uniform). Per-wave B regs: 2ct x 4c x (hi+lo) x 4 = 64 VGPRs, all
// statically indexed. k-loop = LDS reads + MFMA only.
// MFMA operands SWAPPED (weight as A-operand) -> coalesced 16B/8B stores.
// Triple-product split, same order -> bit-identical numerics.

#define KDIM 128
#define APAD 136   // 128 + 8 ushorts pad

// stage 32 rows x 128 cols: thread t loads row t>>3, 16 floats at (t&7)*16.
__device__ inline void stage_a32(const float* __restrict__ A, int bm, int M, int tid,
                                 ushort* __restrict__ Ahi, ushort* __restrict__ Alo) {
    const int m   = tid >> 3;            // 0..31
    const int seg = (tid & 7) * 16;      // float offset
    const int grow = bm + m;
    float f[16];
    if (grow < M) {
        const float* ap = A + (long)grow * KDIM + seg;
        #pragma unroll
        for (int q = 0; q < 4; ++q) {
            float4 a = *(const float4*)(ap + q * 4);
            f[q * 4 + 0] = a.x; f[q * 4 + 1] = a.y;
            f[q * 4 + 2] = a.z; f[q * 4 + 3] = a.w;
        }
    } else {
        #pragma unroll
        for (int i = 0; i < 16; ++i) f[i] = 0.f;
    }
    ushort h[16], l[16];
    #pragma unroll
    for (int i = 0; i < 16; ++i) split_bf16(f[i], h[i], l[i]);
    #pragma unroll
    for (int q = 0; q < 2; ++q) {
        uint4 hw, lw;
        hw.x = (unsigned)h[q*8+0] | ((unsigned)h[q*8+1] << 16);
        hw.y = (unsigned)h[q*8+2] | ((unsigned)h[q*8+3] << 16);
        hw.z = (unsigned)h[q*8+4] | ((unsigned)h[q*8+5] << 16);
        hw.w = (unsigned)h[q*8+6] | ((unsigned)h[q*8+7] << 16);
        lw.x = (unsigned)l[q*8+0] | ((unsigned)l[q*8+1] << 16);
        lw.y = (unsigned)l[q*8+2] | ((unsigned)l[q*8+3] << 16);
        lw.z = (unsigned)l[q*8+4] | ((unsigned)l[q*8+5] << 16);
        lw.w = (unsigned)l[q*8+6] | ((unsigned)l[q*8+7] << 16);
        *(uint4*)&Ahi[m * APAD + seg + q * 8] = hw;
        *(uint4*)&Alo[m * APAD + seg + q * 8] = lw;
    }
}

// Wide: dout=128 dual (256 cols). Grid = 2 * ntiles; block b -> tile b>>1,
// half b&1. Wave covers 32 rows x 32 cols.
__global__ __launch_bounds__(256, 3) void gemm_mfma_wide(
    const float* __restrict__ A,
    const ushort* __restrict__ Bth, const ushort* __restrict__ Btl,
    const float* __restrict__ bias,
    float* __restrict__ S, ushort* __restrict__ T, int M)
{
    __shared__ ushort Ahi[32 * APAD];
    __shared__ ushort Alo[32 * APAD];

    const int tid = threadIdx.x;
    const int wave = tid >> 6;
    const int lane = tid & 63;
    const int lane16 = lane & 15;
    const int quad = lane >> 4;
    const int half = blockIdx.x & 1;              // 0 -> S, 1 -> T
    const int colbase = half * 128 + wave * 32;   // global col in [0,256)
    const int ntiles = (M + 31) >> 5;

    // ---- B prologue: load full-K B fragments for this wave's 32 cols ----
    bf16x8 Bh[4][2], Bl[4][2];
    #pragma unroll
    for (int c = 0; c < 4; ++c) {
        #pragma unroll
        for (int ct = 0; ct < 2; ++ct) {
            const long boff = (long)(colbase + 16 * ct + lane16) * KDIM + c * 32 + quad * 8;
            Bh[c][ct] = *(const bf16x8*)(Bth + boff);
            Bl[c][ct] = *(const bf16x8*)(Btl + boff);
        }
    }

    for (int rt = blockIdx.x >> 1; rt < ntiles; rt += gridDim.x >> 1) {
        const int bm = rt * 32;
        __syncthreads();   // previous iteration's LDS readers done
        stage_a32(A, bm, M, tid, Ahi, Alo);
        __syncthreads();

        f32x4 acc[2][2] = {};

        #pragma unroll
        for (int c = 0; c < 4; ++c) {
            const int k0 = c * 32 + quad * 8;
            bf16x8 ah[2], al[2];
            #pragma unroll
            for (int r = 0; r < 2; ++r) {
                int off = (16 * r + lane16) * APAD + k0;
                ah[r] = *(const bf16x8*)&Ahi[off];
                al[r] = *(const bf16x8*)&Alo[off];
            }
            #pragma unroll
            for (int ct = 0; ct < 2; ++ct) {
                #pragma unroll
                for (int r = 0; r < 2; ++r) {
                    acc[r][ct] = __builtin_amdgcn_mfma_f32_16x16x32_bf16(Bh[c][ct], ah[r], acc[r][ct], 0, 0, 0);
                    acc[r][ct] = __builtin_amdgcn_mfma_f32_16x16x32_bf16(Bl[c][ct], ah[r], acc[r][ct], 0, 0, 0);
                    acc[r][ct] = __builtin_amdgcn_mfma_f32_16x16x32_bf16(Bh[c][ct], al[r], acc[r][ct], 0, 0, 0);
                }
            }
        }

        // Swapped C/D mapping: acc[r][ct][i] = C[bm+16r+lane16][colbase+16ct+quad*4+i]
        #pragma unroll
        for (int ct = 0; ct < 2; ++ct) {
            const int colL = wave * 32 + 16 * ct + quad * 4;   // col within this half
            #pragma unroll
            for (int r = 0; r < 2; ++r) {
                const int row = bm + 16 * r + lane16;
                if (row < M) {
                    if (half == 0) {
                        f32x4 bv = *(const f32x4*)(bias + colL);
                        *(f32x4*)(S + (long)row * 128 + colL) = acc[r][ct] + bv;
                    } else {
                        u16x4 t4;
                        #pragma unroll
                        for (int i = 0; i < 4; ++i) t4[i] = rne_bf16(acc[r][ct][i]);
                        *(u16x4*)(T + (long)row * 128 + colL) = t4;
                    }
                }
            }
        }
    }
}

// Narrow: dout=40 dual (80 cols). Block = 32 rows; wave (rt,cg): rows rt*16,
// cols cg ? {ct3,ct4} : {ct0,ct1,ct2}.  (unchanged from r4)
__global__ __launch_bounds__(256, 4) void gemm_mfma_narrow(
    const float* __restrict__ A,
    const ushort* __restrict__ Bth, const ushort* __restrict__ Btl,
    const float* __restrict__ bias,
    float* __restrict__ S, ushort* __restrict__ T, int M)
{
    __shared__ ushort Ahi[32 * APAD];
    __shared__ ushort Alo[32 * APAD];

    const int tid = threadIdx.x;
    const int wave = tid >> 6;
    const int lane = tid & 63;
    const int lane16 = lane & 15;
    const int quad = lane >> 4;
    const int bm = blockIdx.x * 32;

    const int rt = wave & 1;         // row-tile 0/1
    const int cg = wave >> 1;        // col-group 0/1
    const int ctbase = cg * 3;       // 0 or 3
    const int nct = cg ? 2 : 3;

    stage_a32(A, bm, M, tid, Ahi, Alo);
    __syncthreads();

    f32x4 acc[3] = {};

    #pragma unroll
    for (int c = 0; c < 4; ++c) {
        const int off = (rt * 16 + lane16) * APAD + c * 32 + quad * 8;
        bf16x8 ah = *(const bf16x8*)&Ahi[off];
        bf16x8 al = *(const bf16x8*)&Alo[off];
        #pragma unroll
        for (int j = 0; j < 3; ++j) {
            if (j < nct) {
                const int ct = ctbase + j;
                const long boff = (long)(16 * ct + lane16) * KDIM + c * 32 + quad * 8;
                bf16x8 bh = *(const bf16x8*)(Bth + boff);
                bf16x8 bl = *(const bf16x8*)(Btl + boff);
                acc[j] = __builtin_amdgcn_mfma_f32_16x16x32_bf16(bh, ah, acc[j], 0, 0, 0);
                acc[j] = __builtin_amdgcn_mfma_f32_16x16x32_bf16(bl, ah, acc[j], 0, 0, 0);
                acc[j] = __builtin_amdgcn_mfma_f32_16x16x32_bf16(bh, al, acc[j], 0, 0, 0);
            }
        }
    }

    #pragma unroll
    for (int j = 0; j < 3; ++j) {
        if (j < nct) {
            const int ct = ctbase + j;
            const int col0 = 16 * ct + quad * 4;
            const bool toS = col0 < 40;
            const int row = bm + rt * 16 + lane16;
            if (row < M) {
                if (toS) {
                    f32x4 bv = *(const f32x4*)(bias + col0);
                    *(f32x4*)(S + (long)row * 40 + col0) = acc[j] + bv;
                } else {
                    u16x4 t4;
                    #pragma unroll
                    for (int i = 0; i < 4; ++i) t4[i] = rne_bf16(acc[j][i]);
                    *(u16x4*)(T + (long)row * 40 + (col0 - 40)) = t4;
                }
            }
        }
    }
}

// ---------------- aggregation, wave-per-node, bf16 gather ----------------

template <int RELU>
__global__ __launch_bounds__(256) void agg128_kernel(
    const float* __restrict__ S, const ushort* __restrict__ T,
    const int* __restrict__ off, const int* __restrict__ ssrc,
    float* __restrict__ out, int nnodes)
{
    const int node = (blockIdx.x * 256 + threadIdx.x) >> 6;
    if (node >= nnodes) return;
    const int lane = threadIdx.x & 63;
    const int slot = lane >> 4;          // 0..3
    const int col8 = (lane & 15) * 8;    // 8 features per lane

    const int a = off[node];
    const int b = off[node + 1];

    f32x4 acc0a = {0,0,0,0}, acc0b = {0,0,0,0};
    f32x4 acc1a = {0,0,0,0}, acc1b = {0,0,0,0};

    int i = a;
    for (; i + 8 <= b; i += 8) {
        int s0 = ssrc[i + slot];
        int s1 = ssrc[i + 4 + slot];
        u16x8 v0 = *(const u16x8*)(T + (long)s0 * 128 + col8);
        u16x8 v1 = *(const u16x8*)(T + (long)s1 * 128 + col8);
        #pragma unroll
        for (int j = 0; j < 4; ++j) {
            acc0a[j] += bf16_to_f32(v0[j]);
            acc0b[j] += bf16_to_f32(v0[4 + j]);
            acc1a[j] += bf16_to_f32(v1[j]);
            acc1b[j] += bf16_to_f32(v1[4 + j]);
        }
    }
    for (; i < b; i += 4) {
        int e = i + slot;
        if (e < b) {
            int s = ssrc[e];
            u16x8 v = *(const u16x8*)(T + (long)s * 128 + col8);
            #pragma unroll
            for (int j = 0; j < 4; ++j) {
                acc0a[j] += bf16_to_f32(v[j]);
                acc0b[j] += bf16_to_f32(v[4 + j]);
            }
        }
    }
    f32x4 accA = acc0a + acc1a;
    f32x4 accB = acc0b + acc1b;

    // reduce across the 4 slots
    #pragma unroll
    for (int m = 16; m <= 32; m <<= 1) {
        #pragma unroll
        for (int j = 0; j < 4; ++j) {
            accA[j] += __shfl_xor((float)accA[j], m);
            accB[j] += __shfl_xor((float)accB[j], m);
        }
    }

    if (slot == 0) {
        int deg = b - a;
        float scale = (deg > 0) ? (1.0f / (float)deg) : 0.f;
        f32x4 sA = *(const f32x4*)(S + (long)node * 128 + col8);
        f32x4 sB = *(const f32x4*)(S + (long)node * 128 + col8 + 4);
        f32x4 rA = sA + accA * scale;
        f32x4 rB = sB + accB * scale;
        if (RELU) {
            #pragma unroll
            for (int j = 0; j < 4; ++j) {
                rA[j] = fmaxf(rA[j], 0.f);
                rB[j] = fmaxf(rB[j], 0.f);
            }
        }
        *(f32x4*)(out + (long)node * 128 + col8) = rA;
        *(f32x4*)(out + (long)node * 128 + col8 + 4) = rB;
    }
}

template <int RELU>
__global__ __launch_bounds__(256) void agg40_kernel(
    const float* __restrict__ S, const ushort* __restrict__ T,
    const int* __restrict__ off, const int* __restrict__ ssrc,
    float* __restrict__ out, int nnodes)
{
    const int node = (blockIdx.x * 256 + threadIdx.x) >> 6;
    if (node >= nnodes) return;
    const int lane = threadIdx.x & 63;
    const bool active = lane < 60;
    const int slot = active ? (lane / 10) : 5;   // 0..5
    const int fi = lane % 10;
    const int fo = fi * 4;

    const int a = off[node];
    const int b = off[node + 1];

    f32x4 acc0 = {0,0,0,0}, acc1 = {0,0,0,0};

    int i = a;
    for (; i + 12 <= b; i += 12) {
        int s0 = ssrc[i + slot];
        int s1 = ssrc[i + 6 + slot];
        u16x4 v0 = *(const u16x4*)(T + (long)s0 * 40 + fo);
        u16x4 v1 = *(const u16x4*)(T + (long)s1 * 40 + fo);
        if (active) {
            #pragma unroll
            for (int j = 0; j < 4; ++j) {
                acc0[j] += bf16_to_f32(v0[j]);
                acc1[j] += bf16_to_f32(v1[j]);
            }
        }
    }
    for (; i < b; i += 6) {
        int e = i + slot;
        if (active && e < b) {
            int s = ssrc[e];
            u16x4 v = *(const u16x4*)(T + (long)s * 40 + fo);
            #pragma unroll
            for (int j = 0; j < 4; ++j) acc0[j] += bf16_to_f32(v[j]);
        }
    }
    f32x4 acc = acc0 + acc1;

    f32x4 tot = acc;
    #pragma unroll
    for (int d = 10; d <= 50; d += 10) {
        int srcl = fi + d;
        #pragma unroll
        for (int j = 0; j < 4; ++j) tot[j] += __shfl((float)acc[j], srcl);
    }

    if (lane < 10) {
        int deg = b - a;
        float scale = (deg > 0) ? (1.0f / (float)deg) : 0.f;
        f32x4 s4 = *(const f32x4*)(S + (long)node * 40 + fo);
        f32x4 r = s4 + tot * scale;
        if (RELU) {
            #pragma unroll
            for (int j = 0; j < 4; ++j) r[j] = fmaxf(r[j], 0.f);
        }
        *(f32x4*)(out + (long)node * 40 + fo) = r;
    }
}

// ---------------- launch ----------------

extern "C" void kernel_launch(void* const* d_in, const int* in_sizes, int n_in,
                              void* d_out, int out_size, void* d_ws, size_t ws_size,
                              hipStream_t stream) {
    const float* feat = (const float*)d_in[0];
    const int*   src  = (const int*)d_in[1];
    const int*   dst  = (const int*)d_in[2];
    const float* ws0  = (const float*)d_in[3];
    const float* wn0  = (const float*)d_in[4];
    const float* b0   = (const float*)d_in[5];
    const float* ws1  = (const float*)d_in[6];
    const float* wn1  = (const float*)d_in[7];
    const float* b1   = (const float*)d_in[8];
    const float* ws2  = (const float*)d_in[9];
    const float* wn2  = (const float*)d_in[10];
    const float* b2   = (const float*)d_in[11];

    const int N = N_NODES;
    const int NE = N_EDGES;
    const int NB = (N + 255) / 256;  // 196

    char* ws = (char*)d_ws;
    int*    offsets = (int*)(ws + 0);
    int*    cursor  = (int*)(ws + 200704);
    int*    degi    = (int*)(ws + 401408);
    int*    bsum    = (int*)(ws + 601600);
    int*    ssrc    = (int*)(ws + 603648);
    ushort* Bth0 = (ushort*)(ws + 200704);   // overlap cursor/degi, written after CSR build
    ushort* Btl0 = (ushort*)(ws + 266240);
    ushort* Bth1 = (ushort*)(ws + 331776);
    ushort* Btl1 = (ushort*)(ws + 397312);
    ushort* Bth2 = (ushort*)(ws + 462848);
    ushort* Btl2 = (ushort*)(ws + 483328);
    float*  hbuf = (float*)(ws + 3003904);   // 25.6 MB fp32
    float*  sbuf = (float*)(ws + 28603904);  // 25.6 MB fp32
    ushort* tbuf = (ushort*)(ws + 54203904); // 12.8 MB bf16

    // ---- CSR build ----
    hipMemsetAsync(degi, 0, (size_t)N * sizeof(int), stream);
    count_deg_kernel<<<(NE + 255) / 256, 256, 0, stream>>>(dst, degi, NE);
    block_sums_kernel<<<NB, 256, 0, stream>>>(degi, bsum, N);
    scatter_fused_kernel<<<NB, 256, 0, stream>>>(degi, bsum, offsets, cursor, N, NB);
    fill_csr_kernel<<<(NE + 255) / 256, 256, 0, stream>>>(src, dst, cursor, ssrc, NE);

    // ---- weight pre-convert (one dispatch) ----
    convert_all_w<<<592, 128, 0, stream>>>(ws0, wn0, ws1, wn1, ws2, wn2,
                                           Bth0, Btl0, Bth1, Btl1, Bth2, Btl2);

    const int ntiles = (N + 31) / 32;    // 1563
    const int gw = 2 * ntiles;           // 3126 wide blocks (tile, half)
    const int gn = ntiles;               // 1563 narrow blocks
    const int ga = (N + 3) / 4;          // 12500 agg blocks (4 waves/block)

    // ---- layer 0 ----
    gemm_mfma_wide<<<gw, 256, 0, stream>>>(feat, Bth0, Btl0, b0, sbuf, tbuf, N);
    agg128_kernel<1><<<ga, 256, 0, stream>>>(sbuf, tbuf, offsets, ssrc, hbuf, N);

    // ---- layer 1 ----
    gemm_mfma_wide<<<gw, 256, 0, stream>>>(hbuf, Bth1, Btl1, b1, sbuf, tbuf, N);
    agg128_kernel<1><<<ga, 256, 0, stream>>>(sbuf, tbuf, offsets, ssrc, hbuf, N);

    // ---- layer 2 ----
    gemm_mfma_narrow<<<gn, 256, 0, stream>>>(hbuf, Bth2, Btl2, b2, sbuf, tbuf, N);
    agg40_kernel<0><<<ga, 256, 0, stream>>>(sbuf, tbuf, offsets, ssrc, (float*)d_out, N);
}

// Round 6
// 290.048 us; speedup vs baseline: 1.1557x; 1.1241x over previous
//
#include <hip/hip_runtime.h>

#define N_NODES 50000
#define N_EDGES 600000

typedef short bf16x8 __attribute__((ext_vector_type(8)));
typedef float f32x4  __attribute__((ext_vector_type(4)));
typedef unsigned short u16x8 __attribute__((ext_vector_type(8)));
typedef unsigned short u16x4 __attribute__((ext_vector_type(4)));

// ---------------- bf16 helpers (RNE) ----------------
__device__ inline ushort rne_bf16(float a) {
    union { float f; unsigned u; } v; v.f = a;
    return (ushort)((v.u + 0x7FFFu + ((v.u >> 16) & 1u)) >> 16);
}
__device__ inline float bf16_to_f32(ushort h) {
    return __uint_as_float((unsigned)h << 16);
}
__device__ inline void split_bf16(float a, ushort& hi, ushort& lo) {
    hi = rne_bf16(a);
    float hv = bf16_to_f32(hi);
    lo = rne_bf16(a - hv);
}

// ---------------- CSR build ----------------

__global__ void count_deg_kernel(const int* __restrict__ dst, int* __restrict__ deg, int ne) {
    int e = blockIdx.x * blockDim.x + threadIdx.x;
    if (e < ne) atomicAdd(&deg[dst[e]], 1);
}

__global__ __launch_bounds__(256) void block_sums_kernel(const int* __restrict__ deg,
                                                         int* __restrict__ bsum, int n) {
    __shared__ int s[256];
    int t = threadIdx.x;
    int i = blockIdx.x * 256 + t;
    s[t] = (i < n) ? deg[i] : 0;
    __syncthreads();
    #pragma unroll
    for (int d = 128; d > 0; d >>= 1) {
        if (t < d) s[t] += s[t + d];
        __syncthreads();
    }
    if (t == 0) bsum[blockIdx.x] = s[0];
}

// Fused: re-scan the 196 block sums per block (cheap), then per-block scan of deg.
__global__ __launch_bounds__(256) void scatter_fused_kernel(const int* __restrict__ deg,
                                                            const int* __restrict__ bsum,
                                                            int* __restrict__ off,
                                                            int* __restrict__ cur,
                                                            int n, int nb) {
    __shared__ int s[256];
    int t = threadIdx.x;

    // scan of block sums
    int bv = (t < nb) ? bsum[t] : 0;
    s[t] = bv;
    __syncthreads();
    #pragma unroll
    for (int d = 1; d < 256; d <<= 1) {
        int x = (t >= d) ? s[t - d] : 0;
        __syncthreads();
        s[t] += x;
        __syncthreads();
    }
    int base = (blockIdx.x > 0) ? s[blockIdx.x - 1] : 0;   // exclusive base for this block
    if (blockIdx.x == 0 && t == 0) off[n] = s[255];        // total edges
    __syncthreads();

    // per-block scan of deg
    int i = blockIdx.x * 256 + t;
    int v = (i < n) ? deg[i] : 0;
    s[t] = v;
    __syncthreads();
    #pragma unroll
    for (int d = 1; d < 256; d <<= 1) {
        int x = (t >= d) ? s[t - d] : 0;
        __syncthreads();
        s[t] += x;
        __syncthreads();
    }
    if (i < n) {
        int excl = s[t] - v + base;
        off[i] = excl;
        cur[i] = excl;
    }
}

__global__ void fill_csr_kernel(const int* __restrict__ src, const int* __restrict__ dst,
                                int* __restrict__ cur, int* __restrict__ ssrc, int ne) {
    int e = blockIdx.x * blockDim.x + threadIdx.x;
    if (e < ne) {
        int p = atomicAdd(&cur[dst[e]], 1);
        ssrc[p] = src[e];
    }
}

// ---------------- weight pre-convert (all 3 layers, one dispatch) ----------------
__global__ void convert_all_w(const float* __restrict__ ws0, const float* __restrict__ wn0,
                              const float* __restrict__ ws1, const float* __restrict__ wn1,
                              const float* __restrict__ ws2, const float* __restrict__ wn2,
                              ushort* __restrict__ Bth0, ushort* __restrict__ Btl0,
                              ushort* __restrict__ Bth1, ushort* __restrict__ Btl1,
                              ushort* __restrict__ Bth2, ushort* __restrict__ Btl2) {
    int b = blockIdx.x;
    int k = threadIdx.x;
    const float *Ws, *Wn;
    ushort *H, *L;
    int dout, n;
    if (b < 256)      { n = b;       dout = 128; Ws = ws0; Wn = wn0; H = Bth0; L = Btl0; }
    else if (b < 512) { n = b - 256; dout = 128; Ws = ws1; Wn = wn1; H = Bth1; L = Btl1; }
    else              { n = b - 512; dout = 40;  Ws = ws2; Wn = wn2; H = Bth2; L = Btl2; }
    float w = (n < dout) ? Ws[(long)k * dout + n] : Wn[(long)k * dout + (n - dout)];
    ushort hi, lo;
    split_bf16(w, hi, lo);
    H[n * 128 + k] = hi;
    L[n * 128 + k] = lo;
}

// ---------------- split-bf16 MFMA dual GEMM ----------------
// v6: PERSISTENT blocks with REAL B reuse. r5's bug: gw = 2*ntiles meant each
// block ran its tile loop ONCE, so the per-block B-prologue cost was identical
// to r4's in-loop loads -> no change (measured). Now:
//   wide: 768 blocks (3/CU, all resident, no tail), each half-block processes
//   ~4-5 row tiles with its 64-VGPR B set loaded once.  Double-buffered LDS,
//   ONE barrier per tile; next tile's A is loaded into regs BEFORE the current
//   tile's MFMAs (issue-early / split+write-late) so ~500cy of MFMA covers the
//   A latency.  narrow: same structure, 512 blocks, launch_bounds(256,2) so
//   the 96-VGPR B set can't spill.
// MFMA operands SWAPPED (weight as A-operand) -> coalesced 16B/8B stores.
// Triple-product split, same order -> bit-identical numerics.

#define KDIM 128
#define APAD 136   // 128 + 8 ushorts pad

__device__ inline void load_a16(const float* __restrict__ A, int grow, int M, int seg,
                                float* __restrict__ f) {
    if (grow < M) {
        const float* ap = A + (long)grow * KDIM + seg;
        #pragma unroll
        for (int q = 0; q < 4; ++q) {
            float4 a = *(const float4*)(ap + q * 4);
            f[q * 4 + 0] = a.x; f[q * 4 + 1] = a.y;
            f[q * 4 + 2] = a.z; f[q * 4 + 3] = a.w;
        }
    } else {
        #pragma unroll
        for (int i = 0; i < 16; ++i) f[i] = 0.f;
    }
}

__device__ inline void split_store16(const float* __restrict__ f,
                                     ushort* __restrict__ Ahi, ushort* __restrict__ Alo,
                                     int m, int seg) {
    ushort h[16], l[16];
    #pragma unroll
    for (int i = 0; i < 16; ++i) split_bf16(f[i], h[i], l[i]);
    #pragma unroll
    for (int q = 0; q < 2; ++q) {
        uint4 hw, lw;
        hw.x = (unsigned)h[q*8+0] | ((unsigned)h[q*8+1] << 16);
        hw.y = (unsigned)h[q*8+2] | ((unsigned)h[q*8+3] << 16);
        hw.z = (unsigned)h[q*8+4] | ((unsigned)h[q*8+5] << 16);
        hw.w = (unsigned)h[q*8+6] | ((unsigned)h[q*8+7] << 16);
        lw.x = (unsigned)l[q*8+0] | ((unsigned)l[q*8+1] << 16);
        lw.y = (unsigned)l[q*8+2] | ((unsigned)l[q*8+3] << 16);
        lw.z = (unsigned)l[q*8+4] | ((unsigned)l[q*8+5] << 16);
        lw.w = (unsigned)l[q*8+6] | ((unsigned)l[q*8+7] << 16);
        *(uint4*)&Ahi[m * APAD + seg + q * 8] = hw;
        *(uint4*)&Alo[m * APAD + seg + q * 8] = lw;
    }
}

// Wide: dout=128 dual (256 cols). Block b -> half b&1 (0->S cols 0-127,
// 1->T cols 128-255); grid-stride over row tiles with stride gridDim/2.
__global__ __launch_bounds__(256, 3) void gemm_mfma_wide(
    const float* __restrict__ A,
    const ushort* __restrict__ Bth, const ushort* __restrict__ Btl,
    const float* __restrict__ bias,
    float* __restrict__ S, ushort* __restrict__ T, int M)
{
    __shared__ ushort AhiB[2][32 * APAD];
    __shared__ ushort AloB[2][32 * APAD];

    const int tid = threadIdx.x;
    const int wave = tid >> 6;
    const int lane = tid & 63;
    const int lane16 = lane & 15;
    const int quad = lane >> 4;
    const int half = blockIdx.x & 1;              // 0 -> S, 1 -> T
    const int colbase = half * 128 + wave * 32;   // global col in [0,256)
    const int ntiles = (M + 31) >> 5;
    const int bstride = gridDim.x >> 1;
    const int m   = tid >> 3;                     // staging row 0..31
    const int seg = (tid & 7) * 16;               // staging float offset

    // ---- B prologue: full-K B fragments for this wave's 32 cols (held in regs) ----
    bf16x8 Bh[4][2], Bl[4][2];
    #pragma unroll
    for (int c = 0; c < 4; ++c) {
        #pragma unroll
        for (int ct = 0; ct < 2; ++ct) {
            const long boff = (long)(colbase + 16 * ct + lane16) * KDIM + c * 32 + quad * 8;
            Bh[c][ct] = *(const bf16x8*)(Bth + boff);
            Bl[c][ct] = *(const bf16x8*)(Btl + boff);
        }
    }
    f32x4 bv[2] = {};
    if (half == 0) {
        #pragma unroll
        for (int ct = 0; ct < 2; ++ct)
            bv[ct] = *(const f32x4*)(bias + wave * 32 + 16 * ct + quad * 4);
    }

    int rt = blockIdx.x >> 1;
    if (rt >= ntiles) return;

    float fa[16];
    load_a16(A, rt * 32 + m, M, seg, fa);
    split_store16(fa, &AhiB[0][0], &AloB[0][0], m, seg);
    __syncthreads();

    int cur = 0;
    while (true) {
        const int nrt = rt + bstride;
        float fn[16];
        if (nrt < ntiles) load_a16(A, nrt * 32 + m, M, seg, fn);   // in flight under MFMAs

        const ushort* AH = &AhiB[cur][0];
        const ushort* AL = &AloB[cur][0];

        f32x4 acc[2][2] = {};
        #pragma unroll
        for (int c = 0; c < 4; ++c) {
            const int k0 = c * 32 + quad * 8;
            bf16x8 ah[2], al[2];
            #pragma unroll
            for (int r = 0; r < 2; ++r) {
                const int off = (16 * r + lane16) * APAD + k0;
                ah[r] = *(const bf16x8*)&AH[off];
                al[r] = *(const bf16x8*)&AL[off];
            }
            #pragma unroll
            for (int ct = 0; ct < 2; ++ct) {
                #pragma unroll
                for (int r = 0; r < 2; ++r) {
                    acc[r][ct] = __builtin_amdgcn_mfma_f32_16x16x32_bf16(Bh[c][ct], ah[r], acc[r][ct], 0, 0, 0);
                    acc[r][ct] = __builtin_amdgcn_mfma_f32_16x16x32_bf16(Bl[c][ct], ah[r], acc[r][ct], 0, 0, 0);
                    acc[r][ct] = __builtin_amdgcn_mfma_f32_16x16x32_bf16(Bh[c][ct], al[r], acc[r][ct], 0, 0, 0);
                }
            }
        }

        // Swapped C/D mapping: acc[r][ct][i] = C[rt*32+16r+lane16][colbase+16ct+quad*4+i]
        #pragma unroll
        for (int ct = 0; ct < 2; ++ct) {
            const int colL = wave * 32 + 16 * ct + quad * 4;   // col within this half
            #pragma unroll
            for (int r = 0; r < 2; ++r) {
                const int row = rt * 32 + 16 * r + lane16;
                if (row < M) {
                    if (half == 0) {
                        *(f32x4*)(S + (long)row * 128 + colL) = acc[r][ct] + bv[ct];
                    } else {
                        u16x4 t4;
                        #pragma unroll
                        for (int i = 0; i < 4; ++i) t4[i] = rne_bf16(acc[r][ct][i]);
                        *(u16x4*)(T + (long)row * 128 + colL) = t4;
                    }
                }
            }
        }

        if (nrt >= ntiles) break;
        split_store16(fn, &AhiB[cur ^ 1][0], &AloB[cur ^ 1][0], m, seg);
        __syncthreads();
        cur ^= 1;
        rt = nrt;
    }
}

// Narrow: dout=40 dual (80 cols). Wave (rt,cg): rows rt*16..+16 of the 32-row
// tile; cg=0 -> ct{0,1,2}, cg=1 -> ct{3,4}. B in regs, grid-stride over tiles.
__global__ __launch_bounds__(256, 2) void gemm_mfma_narrow(
    const float* __restrict__ A,
    const ushort* __restrict__ Bth, const ushort* __restrict__ Btl,
    const float* __restrict__ bias,
    float* __restrict__ S, ushort* __restrict__ T, int M)
{
    __shared__ ushort AhiB[2][32 * APAD];
    __shared__ ushort AloB[2][32 * APAD];

    const int tid = threadIdx.x;
    const int wave = tid >> 6;
    const int lane = tid & 63;
    const int lane16 = lane & 15;
    const int quad = lane >> 4;
    const int rtw = wave & 1;        // row-half 0/1
    const int cg = wave >> 1;        // col-group 0/1
    const int ctbase = cg * 3;       // 0 or 3
    const int nct = cg ? 2 : 3;
    const int ntiles = (M + 31) >> 5;
    const int m   = tid >> 3;
    const int seg = (tid & 7) * 16;

    // ---- B prologue (held in regs across all tiles) ----
    bf16x8 Bh[4][3], Bl[4][3];
    #pragma unroll
    for (int c = 0; c < 4; ++c) {
        #pragma unroll
        for (int j = 0; j < 3; ++j) {
            if (j < nct) {
                const long boff = (long)(16 * (ctbase + j) + lane16) * KDIM + c * 32 + quad * 8;
                Bh[c][j] = *(const bf16x8*)(Bth + boff);
                Bl[c][j] = *(const bf16x8*)(Btl + boff);
            }
        }
    }

    int rt = blockIdx.x;
    if (rt >= ntiles) return;

    float fa[16];
    load_a16(A, rt * 32 + m, M, seg, fa);
    split_store16(fa, &AhiB[0][0], &AloB[0][0], m, seg);
    __syncthreads();

    int cur = 0;
    while (true) {
        const int nrt = rt + gridDim.x;
        float fn[16];
        if (nrt < ntiles) load_a16(A, nrt * 32 + m, M, seg, fn);

        const ushort* AH = &AhiB[cur][0];
        const ushort* AL = &AloB[cur][0];

        f32x4 acc[3] = {};
        #pragma unroll
        for (int c = 0; c < 4; ++c) {
            const int off = (rtw * 16 + lane16) * APAD + c * 32 + quad * 8;
            bf16x8 ah = *(const bf16x8*)&AH[off];
            bf16x8 al = *(const bf16x8*)&AL[off];
            #pragma unroll
            for (int j = 0; j < 3; ++j) {
                if (j < nct) {
                    acc[j] = __builtin_amdgcn_mfma_f32_16x16x32_bf16(Bh[c][j], ah, acc[j], 0, 0, 0);
                    acc[j] = __builtin_amdgcn_mfma_f32_16x16x32_bf16(Bl[c][j], ah, acc[j], 0, 0, 0);
                    acc[j] = __builtin_amdgcn_mfma_f32_16x16x32_bf16(Bh[c][j], al, acc[j], 0, 0, 0);
                }
            }
        }

        const int row = rt * 32 + rtw * 16 + lane16;
        #pragma unroll
        for (int j = 0; j < 3; ++j) {
            if (j < nct && row < M) {
                const int col0 = 16 * (ctbase + j) + quad * 4;
                if (col0 < 40) {
                    f32x4 bvv = *(const f32x4*)(bias + col0);
                    *(f32x4*)(S + (long)row * 40 + col0) = acc[j] + bvv;
                } else {
                    u16x4 t4;
                    #pragma unroll
                    for (int i = 0; i < 4; ++i) t4[i] = rne_bf16(acc[j][i]);
                    *(u16x4*)(T + (long)row * 40 + (col0 - 40)) = t4;
                }
            }
        }

        if (nrt >= ntiles) break;
        split_store16(fn, &AhiB[cur ^ 1][0], &AloB[cur ^ 1][0], m, seg);
        __syncthreads();
        cur ^= 1;
        rt = nrt;
    }
}

// ---------------- aggregation, wave-per-node, bf16 gather ----------------

template <int RELU>
__global__ __launch_bounds__(256) void agg128_kernel(
    const float* __restrict__ S, const ushort* __restrict__ T,
    const int* __restrict__ off, const int* __restrict__ ssrc,
    float* __restrict__ out, int nnodes)
{
    const int node = (blockIdx.x * 256 + threadIdx.x) >> 6;
    if (node >= nnodes) return;
    const int lane = threadIdx.x & 63;
    const int slot = lane >> 4;          // 0..3
    const int col8 = (lane & 15) * 8;    // 8 features per lane

    const int a = off[node];
    const int b = off[node + 1];

    f32x4 acc0a = {0,0,0,0}, acc0b = {0,0,0,0};
    f32x4 acc1a = {0,0,0,0}, acc1b = {0,0,0,0};

    int i = a;
    for (; i + 8 <= b; i += 8) {
        int s0 = ssrc[i + slot];
        int s1 = ssrc[i + 4 + slot];
        u16x8 v0 = *(const u16x8*)(T + (long)s0 * 128 + col8);
        u16x8 v1 = *(const u16x8*)(T + (long)s1 * 128 + col8);
        #pragma unroll
        for (int j = 0; j < 4; ++j) {
            acc0a[j] += bf16_to_f32(v0[j]);
            acc0b[j] += bf16_to_f32(v0[4 + j]);
            acc1a[j] += bf16_to_f32(v1[j]);
            acc1b[j] += bf16_to_f32(v1[4 + j]);
        }
    }
    for (; i < b; i += 4) {
        int e = i + slot;
        if (e < b) {
            int s = ssrc[e];
            u16x8 v = *(const u16x8*)(T + (long)s * 128 + col8);
            #pragma unroll
            for (int j = 0; j < 4; ++j) {
                acc0a[j] += bf16_to_f32(v[j]);
                acc0b[j] += bf16_to_f32(v[4 + j]);
            }
        }
    }
    f32x4 accA = acc0a + acc1a;
    f32x4 accB = acc0b + acc1b;

    // reduce across the 4 slots
    #pragma unroll
    for (int m = 16; m <= 32; m <<= 1) {
        #pragma unroll
        for (int j = 0; j < 4; ++j) {
            accA[j] += __shfl_xor((float)accA[j], m);
            accB[j] += __shfl_xor((float)accB[j], m);
        }
    }

    if (slot == 0) {
        int deg = b - a;
        float scale = (deg > 0) ? (1.0f / (float)deg) : 0.f;
        f32x4 sA = *(const f32x4*)(S + (long)node * 128 + col8);
        f32x4 sB = *(const f32x4*)(S + (long)node * 128 + col8 + 4);
        f32x4 rA = sA + accA * scale;
        f32x4 rB = sB + accB * scale;
        if (RELU) {
            #pragma unroll
            for (int j = 0; j < 4; ++j) {
                rA[j] = fmaxf(rA[j], 0.f);
                rB[j] = fmaxf(rB[j], 0.f);
            }
        }
        *(f32x4*)(out + (long)node * 128 + col8) = rA;
        *(f32x4*)(out + (long)node * 128 + col8 + 4) = rB;
    }
}

template <int RELU>
__global__ __launch_bounds__(256) void agg40_kernel(
    const float* __restrict__ S, const ushort* __restrict__ T,
    const int* __restrict__ off, const int* __restrict__ ssrc,
    float* __restrict__ out, int nnodes)
{
    const int node = (blockIdx.x * 256 + threadIdx.x) >> 6;
    if (node >= nnodes) return;
    const int lane = threadIdx.x & 63;
    const bool active = lane < 60;
    const int slot = active ? (lane / 10) : 5;   // 0..5
    const int fi = lane % 10;
    const int fo = fi * 4;

    const int a = off[node];
    const int b = off[node + 1];

    f32x4 acc0 = {0,0,0,0}, acc1 = {0,0,0,0};

    int i = a;
    for (; i + 12 <= b; i += 12) {
        int s0 = ssrc[i + slot];
        int s1 = ssrc[i + 6 + slot];
        u16x4 v0 = *(const u16x4*)(T + (long)s0 * 40 + fo);
        u16x4 v1 = *(const u16x4*)(T + (long)s1 * 40 + fo);
        if (active) {
            #pragma unroll
            for (int j = 0; j < 4; ++j) {
                acc0[j] += bf16_to_f32(v0[j]);
                acc1[j] += bf16_to_f32(v1[j]);
            }
        }
    }
    for (; i < b; i += 6) {
        int e = i + slot;
        if (active && e < b) {
            int s = ssrc[e];
            u16x4 v = *(const u16x4*)(T + (long)s * 40 + fo);
            #pragma unroll
            for (int j = 0; j < 4; ++j) acc0[j] += bf16_to_f32(v[j]);
        }
    }
    f32x4 acc = acc0 + acc1;

    f32x4 tot = acc;
    #pragma unroll
    for (int d = 10; d <= 50; d += 10) {
        int srcl = fi + d;
        #pragma unroll
        for (int j = 0; j < 4; ++j) tot[j] += __shfl((float)acc[j], srcl);
    }

    if (lane < 10) {
        int deg = b - a;
        float scale = (deg > 0) ? (1.0f / (float)deg) : 0.f;
        f32x4 s4 = *(const f32x4*)(S + (long)node * 40 + fo);
        f32x4 r = s4 + tot * scale;
        if (RELU) {
            #pragma unroll
            for (int j = 0; j < 4; ++j) r[j] = fmaxf(r[j], 0.f);
        }
        *(f32x4*)(out + (long)node * 40 + fo) = r;
    }
}

// ---------------- launch ----------------

extern "C" void kernel_launch(void* const* d_in, const int* in_sizes, int n_in,
                              void* d_out, int out_size, void* d_ws, size_t ws_size,
                              hipStream_t stream) {
    const float* feat = (const float*)d_in[0];
    const int*   src  = (const int*)d_in[1];
    const int*   dst  = (const int*)d_in[2];
    const float* ws0  = (const float*)d_in[3];
    const float* wn0  = (const float*)d_in[4];
    const float* b0   = (const float*)d_in[5];
    const float* ws1  = (const float*)d_in[6];
    const float* wn1  = (const float*)d_in[7];
    const float* b1   = (const float*)d_in[8];
    const float* ws2  = (const float*)d_in[9];
    const float* wn2  = (const float*)d_in[10];
    const float* b2   = (const float*)d_in[11];

    const int N = N_NODES;
    const int NE = N_EDGES;
    const int NB = (N + 255) / 256;  // 196

    char* ws = (char*)d_ws;
    int*    offsets = (int*)(ws + 0);
    int*    cursor  = (int*)(ws + 200704);
    int*    degi    = (int*)(ws + 401408);
    int*    bsum    = (int*)(ws + 601600);
    int*    ssrc    = (int*)(ws + 603648);
    ushort* Bth0 = (ushort*)(ws + 200704);   // overlap cursor/degi, written after CSR build
    ushort* Btl0 = (ushort*)(ws + 266240);
    ushort* Bth1 = (ushort*)(ws + 331776);
    ushort* Btl1 = (ushort*)(ws + 397312);
    ushort* Bth2 = (ushort*)(ws + 462848);
    ushort* Btl2 = (ushort*)(ws + 483328);
    float*  hbuf = (float*)(ws + 3003904);   // 25.6 MB fp32
    float*  sbuf = (float*)(ws + 28603904);  // 25.6 MB fp32
    ushort* tbuf = (ushort*)(ws + 54203904); // 12.8 MB bf16

    // ---- CSR build ----
    hipMemsetAsync(degi, 0, (size_t)N * sizeof(int), stream);
    count_deg_kernel<<<(NE + 255) / 256, 256, 0, stream>>>(dst, degi, NE);
    block_sums_kernel<<<NB, 256, 0, stream>>>(degi, bsum, N);
    scatter_fused_kernel<<<NB, 256, 0, stream>>>(degi, bsum, offsets, cursor, N, NB);
    fill_csr_kernel<<<(NE + 255) / 256, 256, 0, stream>>>(src, dst, cursor, ssrc, NE);

    // ---- weight pre-convert (one dispatch) ----
    convert_all_w<<<592, 128, 0, stream>>>(ws0, wn0, ws1, wn1, ws2, wn2,
                                           Bth0, Btl0, Bth1, Btl1, Bth2, Btl2);

    const int gw = 768;                  // persistent wide blocks: 2 halves x 384
    const int gn = 512;                  // persistent narrow blocks
    const int ga = (N + 3) / 4;          // 12500 agg blocks (4 waves/block)

    // ---- layer 0 ----
    gemm_mfma_wide<<<gw, 256, 0, stream>>>(feat, Bth0, Btl0, b0, sbuf, tbuf, N);
    agg128_kernel<1><<<ga, 256, 0, stream>>>(sbuf, tbuf, offsets, ssrc, hbuf, N);

    // ---- layer 1 ----
    gemm_mfma_wide<<<gw, 256, 0, stream>>>(hbuf, Bth1, Btl1, b1, sbuf, tbuf, N);
    agg128_kernel<1><<<ga, 256, 0, stream>>>(sbuf, tbuf, offsets, ssrc, hbuf, N);

    // ---- layer 2 ----
    gemm_mfma_narrow<<<gn, 256, 0, stream>>>(hbuf, Bth2, Btl2, b2, sbuf, tbuf, N);
    agg40_kernel<0><<<ga, 256, 0, stream>>>(sbuf, tbuf, offsets, ssrc, (float*)d_out, N);
}